// Round 2
// baseline (2053.465 us; speedup 1.0000x reference)
//
#include <hip/hip_runtime.h>

#define PIX 32768   // B*H*W total pixels
// sizes: B=8, N=5, C=256, H*W=4096

__device__ __forceinline__ float sigmoidf_(float x){ return 1.f/(1.f+__expf(-x)); }

// S[b][c][pl] = sum_n inputs[b,n,c,pl]
__global__ __launch_bounds__(256) void k_sum(const float* __restrict__ inp, float* __restrict__ S){
    int e = blockIdx.x*256 + threadIdx.x;        // e < 8*256*4096 = 8388608
    int pl = e & 4095;
    int c  = (e >> 12) & 255;
    int b  = e >> 20;
    float s = 0.f;
    #pragma unroll
    for (int n=0;n<5;n++)
        s += inp[(((size_t)((b*5+n)*256+c))<<12) + pl];
    S[e] = s;
}

// D[b][n][j][pl] = sum_c inputs[b,n,c,pl] * wgt_w[j,c]
__global__ __launch_bounds__(256) void k_dots(const float* __restrict__ inp, const float* __restrict__ wgt,
                                              float* __restrict__ D){
    __shared__ float wg[1024];
    for (int s=threadIdx.x; s<1024; s+=256) wg[s] = wgt[s];
    __syncthreads();
    int e = blockIdx.x*256 + threadIdx.x;        // e < 8*5*4096 = 163840
    int pl = e & 4095;
    int bn = e >> 12;                            // b*5+n
    const float* base = inp + (((size_t)bn*256)<<12) + pl;
    float d0=0,d1=0,d2=0,d3=0;
    #pragma unroll 8
    for (int c=0;c<256;c++){
        float v = base[(size_t)c<<12];
        d0 += v*wg[c]; d1 += v*wg[256+c]; d2 += v*wg[512+c]; d3 += v*wg[768+c];
    }
    size_t o = ((size_t)bn*4)<<12;
    D[o+pl]=d0; D[o+4096+pl]=d1; D[o+8192+pl]=d2; D[o+12288+pl]=d3;
}

// G[b][i][j][pl] = sigmoid(D[b,i,j] - D[b, idx(i,j), j]), idx(i,j) = j<i ? j : j+1
__global__ __launch_bounds__(256) void k_gate(const float* __restrict__ D, float* __restrict__ G){
    int e = blockIdx.x*256 + threadIdx.x;        // e < 655360
    int pl = e & 4095;
    int r  = e >> 12;                            // 0..159 = (b*5+i)*4+j
    int j  = r & 3;
    int bi = r >> 2;
    int i  = bi % 5;
    int b  = bi / 5;
    int node = (j < i) ? j : (j+1);
    float w = D[(((size_t)((b*5+i)*4+j))<<12)+pl] - D[(((size_t)((b*5+node)*4+j))<<12)+pl];
    G[e] = sigmoidf_(w);
}

// X[c][p] = m_t = G[b,i,c&3,pl] * (S - h_i)   (k-major layout, p = b*4096+pl global pixel)
__global__ __launch_bounds__(256) void k_buildx(const float* __restrict__ inp, const float* __restrict__ S,
                                                const float* __restrict__ G, float* __restrict__ X, int i){
    int e = blockIdx.x*256 + threadIdx.x;        // e = c*PIX + p, e < 8388608
    int p = e & 32767;
    int c = e >> 15;
    int b = p >> 12, pl = p & 4095;
    float h = inp[(((size_t)((b*5+i)*256+c))<<12)+pl];
    float s = S[(((size_t)(b*256+c))<<12)+pl];
    float g = G[(((size_t)((b*5+i)*4+(c&3)))<<12)+pl];
    X[e] = g*(s-h);
}

// Tiled fp32 GEMM: C[p][o] = sum_k A[k][p] * W[o][k], 128x128 tiles, K=512.
// A: k<256 -> Alo (=X, m_t); k>=256 -> EPI0: inputs h_t rows (stride 4096), EPI1: X2h.
// EPI0 epilogue: sigmoid; o<256 -> U[o][p]=u ; o>=256 -> X2h[o-256][p] = h_t*r
// EPI1 epilogue: tanh; h_new = h*(1-u)+o*u ; out = h_new*gamma + h
template<int EPI>
__global__ __launch_bounds__(256) void k_gemm(
        const float* __restrict__ Alo, const float* __restrict__ AhiX,
        const float* __restrict__ inp,
        const float* __restrict__ W0, const float* __restrict__ W1,
        const float* __restrict__ bias0, const float* __restrict__ bias1,
        float* __restrict__ out0, float* __restrict__ out1,
        const float* __restrict__ Uin, const float* __restrict__ gamma_p, int i)
{
    __shared__ float xs[32][132];
    __shared__ float wt[32][132];
    int t  = threadIdx.x;
    int m0 = blockIdx.x * 128;                   // pixel base (within one b: 128 | 4096)
    int n0 = blockIdx.y * 128;                   // output-channel base
    int b  = m0 >> 12;
    int pl0 = m0 & 4095;

    bool is_r = (EPI==0) && (n0 >= 256);
    const float* W    = is_r ? W1 : W0;
    const float* bvec = is_r ? bias1 : bias0;
    int nrel = is_r ? (n0 - 256) : n0;

    const float* AhiInp = inp + (((size_t)((b*5+i)*256))<<12) + pl0;  // h_t rows, stride 4096

    float acc[8][8];
    #pragma unroll
    for (int a=0;a<8;a++){
        #pragma unroll
        for (int o=0;o<8;o++) acc[a][o]=0.f;
    }

    for (int kb=0; kb<16; ++kb){
        int k0 = kb*32;
        // stage A tile: 32 k x 128 px
        #pragma unroll
        for (int q=0;q<4;q++){
            int s4 = t + q*256;                  // 0..1023
            int kk = s4 >> 5;
            int px4 = (s4 & 31) << 2;
            int k = k0 + kk;
            float4 v;
            if (k < 256){
                v = *(const float4*)&Alo[((size_t)k<<15) + m0 + px4];
            } else {
                if (EPI==0) v = *(const float4*)&AhiInp[((size_t)(k-256)<<12) + px4];
                else        v = *(const float4*)&AhiX[((size_t)(k-256)<<15) + m0 + px4];
            }
            *(float4*)&xs[kk][px4] = v;
        }
        // stage W tile: 128 o x 32 k, transposed into wt[k][o]
        #pragma unroll
        for (int q=0;q<4;q++){
            int s4 = t + q*256;
            int oo = s4 >> 3;                    // 0..127
            int k4 = (s4 & 7) << 2;              // 0..28
            float4 v = *(const float4*)(W + (size_t)(nrel+oo)*512 + k0 + k4);
            wt[k4+0][oo]=v.x; wt[k4+1][oo]=v.y; wt[k4+2][oo]=v.z; wt[k4+3][oo]=v.w;
        }
        __syncthreads();
        int px0 = (t & 15) * 8;
        int o0  = (t >> 4) * 8;
        #pragma unroll 8
        for (int kk=0;kk<32;kk++){
            float4 x0 = *(const float4*)&xs[kk][px0];
            float4 x1 = *(const float4*)&xs[kk][px0+4];
            float4 w0 = *(const float4*)&wt[kk][o0];
            float4 w1 = *(const float4*)&wt[kk][o0+4];
            float xv[8] = {x0.x,x0.y,x0.z,x0.w,x1.x,x1.y,x1.z,x1.w};
            float wv[8] = {w0.x,w0.y,w0.z,w0.w,w1.x,w1.y,w1.z,w1.w};
            #pragma unroll
            for (int a=0;a<8;a++){
                #pragma unroll
                for (int o=0;o<8;o++) acc[a][o] += xv[a]*wv[o];
            }
        }
        __syncthreads();
    }

    int px0 = (t & 15) * 8;
    int o0  = (t >> 4) * 8;
    int pxg = m0 + px0;                          // global pixel base of this thread's 8 px
    int pl  = pl0 + px0;
    float gm = (EPI==1) ? gamma_p[0] : 0.f;
    size_t hbase = (((size_t)((b*5+i)*256))<<12) + pl;

    #pragma unroll
    for (int o=0;o<8;o++){
        int oc = nrel + o0 + o;                  // channel within its 256-block
        float bv = bvec[oc];
        float v[8];
        #pragma unroll
        for (int a=0;a<8;a++) v[a] = acc[a][o] + bv;
        if (EPI==0){
            #pragma unroll
            for (int a=0;a<8;a++) v[a] = sigmoidf_(v[a]);
            if (!is_r){
                *(float4*)&out0[((size_t)oc<<15)+pxg]   = make_float4(v[0],v[1],v[2],v[3]);
                *(float4*)&out0[((size_t)oc<<15)+pxg+4] = make_float4(v[4],v[5],v[6],v[7]);
            } else {
                const float* hp = inp + hbase + ((size_t)oc<<12);
                float4 h0 = *(const float4*)hp;
                float4 h1 = *(const float4*)(hp+4);
                *(float4*)&out1[((size_t)oc<<15)+pxg]   = make_float4(v[0]*h0.x,v[1]*h0.y,v[2]*h0.z,v[3]*h0.w);
                *(float4*)&out1[((size_t)oc<<15)+pxg+4] = make_float4(v[4]*h1.x,v[5]*h1.y,v[6]*h1.z,v[7]*h1.w);
            }
        } else {
            const float* hp = inp + hbase + ((size_t)oc<<12);
            float4 h0 = *(const float4*)hp;
            float4 h1 = *(const float4*)(hp+4);
            float4 u0 = *(const float4*)&Uin[((size_t)oc<<15)+pxg];
            float4 u1 = *(const float4*)&Uin[((size_t)oc<<15)+pxg+4];
            float hh[8] = {h0.x,h0.y,h0.z,h0.w,h1.x,h1.y,h1.z,h1.w};
            float uu[8] = {u0.x,u0.y,u0.z,u0.w,u1.x,u1.y,u1.z,u1.w};
            float res[8];
            #pragma unroll
            for (int a=0;a<8;a++){
                float e2 = __expf(2.f*v[a]);
                float th = 1.f - 2.f/(e2+1.f);   // tanh
                float hn = hh[a]*(1.f-uu[a]) + th*uu[a];
                res[a] = hn*gm + hh[a];
            }
            float* op = out0 + hbase + ((size_t)oc<<12);
            *(float4*)op     = make_float4(res[0],res[1],res[2],res[3]);
            *(float4*)(op+4) = make_float4(res[4],res[5],res[6],res[7]);
        }
    }
}

extern "C" void kernel_launch(void* const* d_in, const int* in_sizes, int n_in,
                              void* d_out, int out_size, void* d_ws, size_t ws_size,
                              hipStream_t stream) {
    const float* inputs = (const float*)d_in[0];
    const float* wgt_w  = (const float*)d_in[1];
    const float* w_r    = (const float*)d_in[2];
    const float* b_r    = (const float*)d_in[3];
    const float* w_u    = (const float*)d_in[4];
    const float* b_u    = (const float*)d_in[5];
    const float* w_o    = (const float*)d_in[6];
    const float* b_o    = (const float*)d_in[7];
    const float* gamma  = (const float*)d_in[8];
    float* out = (float*)d_out;

    float* S   = (float*)d_ws;                 // 8388608
    float* D   = S   + 8388608;                // 655360
    float* G   = D   + 655360;                 // 655360
    float* X   = G   + 655360;                 // 8388608  (m_t, [256][32768])
    float* X2h = X   + 8388608;                // 8388608  (h_t*r, [256][32768])
    float* U   = X2h + 8388608;                // 8388608  (u, [256][32768])

    k_sum <<<32768, 256, 0, stream>>>(inputs, S);
    k_dots<<<640,   256, 0, stream>>>(inputs, wgt_w, D);
    k_gate<<<2560,  256, 0, stream>>>(D, G);
    for (int i=0;i<5;i++){
        k_buildx<<<32768, 256, 0, stream>>>(inputs, S, G, X, i);
        k_gemm<0><<<dim3(256,4), 256, 0, stream>>>(X, nullptr, inputs, w_u, w_r, b_u, b_r,
                                                   U, X2h, nullptr, gamma, i);
        k_gemm<1><<<dim3(256,2), 256, 0, stream>>>(X, X2h, inputs, w_o, nullptr, b_o, nullptr,
                                                   out, nullptr, U, gamma, i);
    }
}

// Round 3
// 866.436 us; speedup vs baseline: 2.3700x; 2.3700x over previous
//
#include <hip/hip_runtime.h>

// sizes: B=8, N=5, C=256, H*W=4096, PIX = 32768 global pixels
typedef __attribute__((ext_vector_type(8))) short short8;
typedef __attribute__((ext_vector_type(4))) float f32x4;
typedef __attribute__((ext_vector_type(8))) unsigned short us8;
typedef __attribute__((ext_vector_type(4))) unsigned short us4;

__device__ __forceinline__ float sigmoidf_(float x){ return 1.f/(1.f+__expf(-x)); }
__device__ __forceinline__ unsigned short f2bf(float f){
    union{float f; unsigned int u;} x; x.f = f;
    unsigned int r = x.u + 0x7fffu + ((x.u>>16)&1u);
    return (unsigned short)(r>>16);
}
#define GAS(p) ((const __attribute__((address_space(1))) void*)(uintptr_t)(p))
#define LAS(p) ((__attribute__((address_space(3))) void*)(uintptr_t)(p))

// S[b][c][pl] = sum_n inputs[b,n,c,pl]
__global__ __launch_bounds__(256) void k_sum(const float* __restrict__ inp, float* __restrict__ S){
    int e = blockIdx.x*256 + threadIdx.x;
    int pl = e & 4095;
    int c  = (e >> 12) & 255;
    int b  = e >> 20;
    float s = 0.f;
    #pragma unroll
    for (int n=0;n<5;n++)
        s += inp[(((size_t)((b*5+n)*256+c))<<12) + pl];
    S[e] = s;
}

// D[b][n][j][pl] = sum_c inputs[b,n,c,pl] * wgt_w[j,c]
__global__ __launch_bounds__(256) void k_dots(const float* __restrict__ inp, const float* __restrict__ wgt,
                                              float* __restrict__ D){
    __shared__ float wg[1024];
    for (int s=threadIdx.x; s<1024; s+=256) wg[s] = wgt[s];
    __syncthreads();
    int e = blockIdx.x*256 + threadIdx.x;
    int pl = e & 4095;
    int bn = e >> 12;
    const float* base = inp + (((size_t)bn*256)<<12) + pl;
    float d0=0,d1=0,d2=0,d3=0;
    #pragma unroll 8
    for (int c=0;c<256;c++){
        float v = base[(size_t)c<<12];
        d0 += v*wg[c]; d1 += v*wg[256+c]; d2 += v*wg[512+c]; d3 += v*wg[768+c];
    }
    size_t o = ((size_t)bn*4)<<12;
    D[o+pl]=d0; D[o+4096+pl]=d1; D[o+8192+pl]=d2; D[o+12288+pl]=d3;
}

// G[b][i][j][pl] = sigmoid(D[b,i,j] - D[b, idx(i,j), j])
__global__ __launch_bounds__(256) void k_gate(const float* __restrict__ D, float* __restrict__ G){
    int e = blockIdx.x*256 + threadIdx.x;
    int pl = e & 4095;
    int r  = e >> 12;
    int j  = r & 3;
    int bi = r >> 2;
    int i  = bi % 5;
    int b  = bi / 5;
    int node = (j < i) ? j : (j+1);
    float w = D[(((size_t)((b*5+i)*4+j))<<12)+pl] - D[(((size_t)((b*5+node)*4+j))<<12)+pl];
    G[e] = sigmoidf_(w);
}

// Weight prep: dst blocked [kb][OCN][64] bf16 from fp32 [oc][512] rows.
// oc<256 -> w0, else w1 (OCN=512 case).
__global__ __launch_bounds__(256) void k_wp(const float* __restrict__ w0, const float* __restrict__ w1,
                                            unsigned short* __restrict__ dst, int OCN){
    int tid = blockIdx.x*256 + threadIdx.x;      // < OCN*128
    int d = tid*4;
    int kk = d & 63;
    int row = d >> 6;
    int oc = row & (OCN-1);
    int kb = row / OCN;
    int k  = kb*64 + kk;
    const float* src = (oc < 256) ? w0 : w1;
    int ocr = (oc < 256) ? oc : oc-256;
    float4 v = *(const float4*)&src[(size_t)ocr*512 + k];
    us4 pk; pk.x=f2bf(v.x); pk.y=f2bf(v.y); pk.z=f2bf(v.z); pk.w=f2bf(v.w);
    *(us4*)&dst[d] = pk;
}

// Fused: m_t = G[c&3]*(S-h) and h_t, both bf16, transposed c-major -> blocked [kb][p][64].
// grid: 4 c-tiles x 512 p-tiles = 2048 blocks
__global__ __launch_bounds__(256) void k_bx(const float* __restrict__ inp, const float* __restrict__ S,
                                            const float* __restrict__ G,
                                            unsigned short* __restrict__ Alo, unsigned short* __restrict__ Ahi,
                                            int i){
    __shared__ unsigned short tm[64][72];
    __shared__ unsigned short th[64][72];
    int t  = threadIdx.x;
    int c0 = (blockIdx.x & 3) << 6;
    int p0 = (blockIdx.x >> 2) << 6;
    int b  = p0 >> 12, pl0 = p0 & 4095;
    #pragma unroll
    for (int q=0;q<4;q++){
        int s  = t + q*256;          // 0..1023
        int c  = s >> 4;             // 0..63
        int pc = (s & 15) << 2;      // 0..60
        int cc = c0 + c;
        float4 h4 = *(const float4*)&inp[(((size_t)((b*5+i)*256+cc))<<12) + pl0 + pc];
        float4 s4 = *(const float4*)&S[(((size_t)(b*256+cc))<<12) + pl0 + pc];
        float4 g4 = *(const float4*)&G[(((size_t)((b*5+i)*4+(cc&3)))<<12) + pl0 + pc];
        tm[c][pc+0]=f2bf(g4.x*(s4.x-h4.x)); tm[c][pc+1]=f2bf(g4.y*(s4.y-h4.y));
        tm[c][pc+2]=f2bf(g4.z*(s4.z-h4.z)); tm[c][pc+3]=f2bf(g4.w*(s4.w-h4.w));
        th[c][pc+0]=f2bf(h4.x); th[c][pc+1]=f2bf(h4.y);
        th[c][pc+2]=f2bf(h4.z); th[c][pc+3]=f2bf(h4.w);
    }
    __syncthreads();
    int kb = c0 >> 6;
    #pragma unroll
    for (int q=0;q<2;q++){
        int s    = t + q*256;        // 0..511
        int p    = s >> 3;           // 0..63
        int cseg = (s & 7) << 3;     // 0..56
        size_t dst = ((size_t)kb*32768 + p0 + p)*64 + cseg;
        us8 vm, vh;
        #pragma unroll
        for (int j=0;j<8;j++){ vm[j]=tm[cseg+j][p]; vh[j]=th[cseg+j][p]; }
        *(us8*)&Alo[dst] = vm;
        *(us8*)&Ahi[dst] = vh;
    }
}

// MFMA GEMM: D[oc][p] = sum_k W[oc][k]*Act[p][k].  A-operand = weights, B = pixels.
// Tile: 128 oc x 128 p, BK=64, 4 waves (2x2 of 64x64), 4x4 frags of 16x16x32 bf16.
// Act blocked: kb<4 -> Alo (m_t), kb>=4 -> Ahi (EPI0: h_t, EPI1: h*r).
// EPI0 (OCN=512): oc<256 -> U[oc][p]=sigmoid(v+b_u); oc>=256 -> A1hi blocked = bf16(sigmoid(v+b_r)*h)
// EPI1 (OCN=256): out = (h*(1-u)+tanh(v+b_o)*u)*gamma + h
template<int EPI>
__global__ __launch_bounds__(256) void k_mm(
        const unsigned short* __restrict__ Alo, const unsigned short* __restrict__ Ahi,
        const unsigned short* __restrict__ Wb,
        const float* __restrict__ inp, const float* __restrict__ b0, const float* __restrict__ b1,
        float* __restrict__ U, unsigned short* __restrict__ A1hi, float* __restrict__ outp,
        const float* __restrict__ gamma_p, int i)
{
    constexpr int OCN = EPI ? 256 : 512;
    __shared__ unsigned short As[128*64];   // weights tile [oc][64]
    __shared__ unsigned short Bs[128*64];   // pixel tile  [p][64]
    int t  = threadIdx.x, wv = t>>6, ln = t&63;
    int p0 = blockIdx.x*128, oc0 = blockIdx.y*128;
    int wm = (wv>>1)*64, wn = (wv&1)*64;
    int row = ln & 15, quad = ln >> 4, kq = quad*8;

    f32x4 acc[4][4];
    f32x4 z = {0.f,0.f,0.f,0.f};
    #pragma unroll
    for (int a=0;a<4;a++){
        #pragma unroll
        for (int o=0;o<4;o++) acc[a][o]=z;
    }

    for (int kb=0; kb<8; ++kb){
        const unsigned short* gA = (kb<4) ? (Alo + ((size_t)kb*32768 + p0)*64)
                                          : (Ahi + ((size_t)(kb-4)*32768 + p0)*64);
        const unsigned short* gW = Wb + ((size_t)kb*OCN + oc0)*64;
        #pragma unroll
        for (int q=0;q<4;q++){
            int off = (wv*4+q)*512;      // ushort units, 1024B chunks
            __builtin_amdgcn_global_load_lds(GAS(gA + off + ln*8), LAS(Bs + off + ln*8), 16, 0, 0);
            __builtin_amdgcn_global_load_lds(GAS(gW + off + ln*8), LAS(As + off + ln*8), 16, 0, 0);
        }
        __syncthreads();
        #pragma unroll
        for (int ks=0; ks<2; ks++){
            short8 a[4], b[4];
            #pragma unroll
            for (int f=0; f<4; f++){
                a[f] = *(const short8*)&As[(wm+f*16+row)*64 + ks*32 + kq];
                b[f] = *(const short8*)&Bs[(wn+f*16+row)*64 + ks*32 + kq];
            }
            #pragma unroll
            for (int fm=0; fm<4; fm++){
                #pragma unroll
                for (int fn=0; fn<4; fn++)
                    acc[fm][fn] = __builtin_amdgcn_mfma_f32_16x16x32_bf16(a[fm], b[fn], acc[fm][fn], 0,0,0);
            }
        }
        __syncthreads();
    }

    float gm = EPI ? gamma_p[0] : 0.f;
    #pragma unroll
    for (int fn=0; fn<4; fn++){
        int p  = p0 + wn + fn*16 + row;
        int b  = p >> 12, pl = p & 4095;
        size_t hb = (((size_t)((b*5+i)*256))<<12) + pl;
        #pragma unroll
        for (int fm=0; fm<4; fm++){
            int ocb = oc0 + wm + fm*16 + quad*4;
            if (EPI==0){
                if (oc0 < 256){
                    #pragma unroll
                    for (int r=0;r<4;r++){
                        int oc = ocb + r;
                        U[(size_t)oc*32768 + p] = sigmoidf_(acc[fm][fn][r] + b0[oc]);
                    }
                } else {
                    int kb2 = ocb - 256;             // mult of 4
                    us4 pk;
                    #pragma unroll
                    for (int r=0;r<4;r++){
                        int c = kb2 + r;
                        float rg = sigmoidf_(acc[fm][fn][r] + b1[c]);
                        float h  = inp[hb + ((size_t)c<<12)];
                        pk[r] = f2bf(rg*h);
                    }
                    *(us4*)&A1hi[((size_t)(kb2>>6)*32768 + p)*64 + (kb2&63)] = pk;
                }
            } else {
                #pragma unroll
                for (int r=0;r<4;r++){
                    int oc = ocb + r;
                    float v  = acc[fm][fn][r] + b0[oc];
                    float e2 = __expf(2.f*v);
                    float thv = 1.f - 2.f/(e2+1.f);
                    float u  = U[(size_t)oc*32768 + p];
                    float h  = inp[hb + ((size_t)oc<<12)];
                    float hn = h*(1.f-u) + thv*u;
                    outp[hb + ((size_t)oc<<12)] = hn*gm + h;
                }
            }
        }
    }
}

extern "C" void kernel_launch(void* const* d_in, const int* in_sizes, int n_in,
                              void* d_out, int out_size, void* d_ws, size_t ws_size,
                              hipStream_t stream) {
    const float* inputs = (const float*)d_in[0];
    const float* wgt_w  = (const float*)d_in[1];
    const float* w_r    = (const float*)d_in[2];
    const float* b_r    = (const float*)d_in[3];
    const float* w_u    = (const float*)d_in[4];
    const float* b_u    = (const float*)d_in[5];
    const float* w_o    = (const float*)d_in[6];
    const float* b_o    = (const float*)d_in[7];
    const float* gamma  = (const float*)d_in[8];
    float* out = (float*)d_out;

    float* S = (float*)d_ws;                   // 8388608 f
    float* D = S + 8388608;                    // 655360 f
    float* G = D + 655360;                     // 655360 f
    float* U = G + 655360;                     // 8388608 f
    unsigned short* Alo  = (unsigned short*)(U + 8388608);  // 8388608 us (m_t blocked)
    unsigned short* Ahi  = Alo + 8388608;                   // h_t blocked
    unsigned short* A1hi = Ahi + 8388608;                   // h*r blocked
    unsigned short* Wc0  = A1hi + 8388608;                  // 512*512
    unsigned short* Wc1  = Wc0 + 262144;                    // 256*512

    k_sum <<<32768, 256, 0, stream>>>(inputs, S);
    k_dots<<<640,   256, 0, stream>>>(inputs, wgt_w, D);
    k_gate<<<2560,  256, 0, stream>>>(D, G);
    k_wp  <<<256,   256, 0, stream>>>(w_u, w_r, Wc0, 512);
    k_wp  <<<128,   256, 0, stream>>>(w_o, w_o, Wc1, 256);
    for (int i=0;i<5;i++){
        k_bx<<<2048, 256, 0, stream>>>(inputs, S, G, Alo, Ahi, i);
        k_mm<0><<<dim3(256,4), 256, 0, stream>>>(Alo, Ahi, Wc0, inputs, b_u, b_r,
                                                 U, A1hi, nullptr, gamma, i);
        k_mm<1><<<dim3(256,2), 256, 0, stream>>>(Alo, A1hi, Wc1, inputs, b_o, nullptr,
                                                 U, nullptr, out, gamma, i);
    }
}